// Round 13
// baseline (342.563 us; speedup 1.0000x reference)
//
#include <hip/hip_runtime.h>

#define B_ 4
#define NH_ 32
#define SQ_ 512
#define HD_ 128
#define MLEN_ 3584
#define KT_ 4096           // MLEN_ + SQ_
#define QB_ 128
#define KB_ 64
#define NTILE_ 64          // KT_ / KB_
#define MEMTILES_ 56       // MLEN_ / KB_
#define HTILES_ 32         // NTILE_ / 2 (per split half)

typedef float f32x4 __attribute__((ext_vector_type(4)));
typedef short s16x8 __attribute__((ext_vector_type(8)));

__device__ __forceinline__ f32x4 MFMA16(s16x8 a, s16x8 b, f32x4 c) {
    return __builtin_amdgcn_mfma_f32_16x16x32_bf16(a, b, c, 0, 0, 0);
}

__device__ __forceinline__ s16x8 cvt8(float4 a, float4 b) {
    union { s16x8 v; __bf16 h[8]; } u;
    u.h[0] = (__bf16)a.x; u.h[1] = (__bf16)a.y;
    u.h[2] = (__bf16)a.z; u.h[3] = (__bf16)a.w;
    u.h[4] = (__bf16)b.x; u.h[5] = (__bf16)b.y;
    u.h[6] = (__bf16)b.z; u.h[7] = (__bf16)b.w;
    return u.v;
}

// Split-KV 2-way over the R6 inner loop (unmodified dataflow, 64 VGPR):
// grid 1024 = 4 independent blocks/CU (vs R6's 2). Each block does half the
// KV tiles and writes unnormalized partial O + (m,l); a reduce pass combines.
// QB=128 preserved -> FETCH unchanged (R11 showed QB=64 doubles it).
__launch_bounds__(512)
__global__ void attn_split_kernel(const float* __restrict__ q, const float* __restrict__ k,
                                  const float* __restrict__ v, const float* __restrict__ mask,
                                  const float* __restrict__ mem,
                                  float* __restrict__ opart, float2* __restrict__ ml)
{
    __shared__ __bf16 Klds[KB_ * HD_];        // 16 KB, swizzled rows
    __shared__ __bf16 Vt[HD_ * KB_];          // 16 KB, transposed + swizzled

    const int tid  = threadIdx.x;
    const int lane = tid & 63;
    const int w    = tid >> 6;                // 0..7
    const int l15  = lane & 15;
    const int l4   = lane >> 4;               // 0..3
    const int xv   = (lane & 7) << 4;

    // bid: [half:1][qt:2][bh:7] -> same head's 8 blocks are bid%128-equal (same XCD)
    const int half = blockIdx.x >> 9;
    const int qt   = (blockIdx.x >> 7) & 3;
    const int pair = blockIdx.x & 127;
    const int b    = pair >> 5;
    const int h    = pair & 31;
    const int q0   = qt * QB_;
    const int t0   = half * HTILES_;

    // ---- Q fragments (B-operand; lane l15 = q-row, k-elem = l4*8+j = d) ----
    const float scale = 0.088388347648318447f;   // 1/sqrt(128)
    s16x8 qf[4];
    {
        const float* qbase = q + (((size_t)(b * NH_ + h)) * SQ_ + q0 + w * 16 + l15) * HD_;
        #pragma unroll
        for (int kc = 0; kc < 4; ++kc) {
            const float* p = qbase + kc * 32 + l4 * 8;
            float4 a = *(const float4*)p;
            float4 c = *(const float4*)(p + 4);
            a.x *= scale; a.y *= scale; a.z *= scale; a.w *= scale;
            c.x *= scale; c.y *= scale; c.z *= scale; c.w *= scale;
            qf[kc] = cvt8(a, c);
        }
    }

    f32x4 acc[8];
    #pragma unroll
    for (int n = 0; n < 8; ++n) acc[n] = (f32x4){0.f, 0.f, 0.f, 0.f};

    float mrun = -3.0e38f, lrun = 0.f;        // per-lane stats for q = w*16 + l15

    const float* maskrow = mask + ((size_t)b * SQ_ + q0 + w * 16 + l15) * KT_;

    for (int t = t0; t < t0 + HTILES_; ++t) {
        const int kv0 = t * KB_;
        const float *srcK, *srcV;
        int rstride;
        if (t < MEMTILES_) {
            const float* mrow = mem + ((size_t)b * MLEN_ + kv0) * (2 * NH_ * HD_) + h * HD_;
            srcK = mrow;
            srcV = mrow + NH_ * HD_;
            rstride = 2 * NH_ * HD_;
        } else {
            size_t off = (((size_t)b * NH_ + h) * SQ_ + (kv0 - MLEN_)) * HD_;
            srcK = k + off;
            srcV = v + off;
            rstride = HD_;
        }

        __syncthreads();   // previous tile's LDS reads complete

        // ---- K stage ----
        #pragma unroll
        for (int it = 0; it < 2; ++it) {
            int idx = tid + it * 512;
            int row = idx >> 4, cg = idx & 15;
            const float* p = srcK + (size_t)row * rstride + cg * 8;
            float4 a = *(const float4*)p;
            float4 c = *(const float4*)(p + 4);
            s16x8 vv = cvt8(a, c);
            int byte = row * 256 + ((cg * 16) ^ ((row & 7) << 4));
            *(s16x8*)((char*)Klds + byte) = vv;
        }
        // ---- V stage (transposed) ----
        #pragma unroll
        for (int it = 0; it < 2; ++it) {
            int idx = tid + it * 512;
            int hd = idx & 127, kvb = idx >> 7;
            const float* p = srcV + (size_t)(kvb * 8) * rstride + hd;
            union { s16x8 v; __bf16 hh[8]; } u;
            #pragma unroll
            for (int j = 0; j < 8; ++j) u.hh[j] = (__bf16)p[(size_t)j * rstride];
            int byte = hd * 128 + ((kvb * 16) ^ ((hd & 7) << 4));
            *(s16x8*)((char*)Vt + byte) = u.v;
        }

        __syncthreads();   // tile staged

        // ---- mask loads ----
        f32x4 mk[4];
        #pragma unroll
        for (int mt = 0; mt < 4; ++mt)
            mk[mt] = *(const f32x4*)(maskrow + kv0 + mt * 16 + l4 * 4);

        // ---- S^T = K @ Q^T ----
        f32x4 st[4];
        #pragma unroll
        for (int mt = 0; mt < 4; ++mt) st[mt] = (f32x4){0.f, 0.f, 0.f, 0.f};
        #pragma unroll
        for (int mt = 0; mt < 4; ++mt) {
            #pragma unroll
            for (int kc = 0; kc < 4; ++kc) {
                s16x8 kf = *(const s16x8*)((const char*)Klds +
                            (mt * 16 + l15) * 256 + (((kc * 4 + l4) * 16) ^ xv));
                st[mt] = MFMA16(kf, qf[kc], st[mt]);
            }
        }

        // ---- mask apply ----
        #pragma unroll
        for (int mt = 0; mt < 4; ++mt)
            #pragma unroll
            for (int r = 0; r < 4; ++r)
                st[mt][r] = fmaf(mk[mt][r], st[mt][r] + 10000.f, -10000.f);

        // ---- in-register softmax over kv ----
        float x0 = fmaxf(fmaxf(st[0][0], st[0][1]), fmaxf(st[0][2], st[0][3]));
        float x1 = fmaxf(fmaxf(st[1][0], st[1][1]), fmaxf(st[1][2], st[1][3]));
        float x2 = fmaxf(fmaxf(st[2][0], st[2][1]), fmaxf(st[2][2], st[2][3]));
        float x3 = fmaxf(fmaxf(st[3][0], st[3][1]), fmaxf(st[3][2], st[3][3]));
        float rm = fmaxf(fmaxf(x0, x1), fmaxf(x2, x3));
        rm = fmaxf(rm, __shfl_xor(rm, 16));
        rm = fmaxf(rm, __shfl_xor(rm, 32));

        if (!__all(rm <= mrun + 8.f)) {       // defer-max
            float nm = fmaxf(mrun, rm);
            float al = __expf(mrun - nm);
            mrun = nm;
            lrun *= al;
            float alr0 = __shfl(al, l4 * 4 + 0);
            float alr1 = __shfl(al, l4 * 4 + 1);
            float alr2 = __shfl(al, l4 * 4 + 2);
            float alr3 = __shfl(al, l4 * 4 + 3);
            #pragma unroll
            for (int nn = 0; nn < 8; ++nn) {
                acc[nn][0] *= alr0; acc[nn][1] *= alr1;
                acc[nn][2] *= alr2; acc[nn][3] *= alr3;
            }
        }

        float rs = 0.f;
        #pragma unroll
        for (int mt = 0; mt < 4; ++mt) {
            #pragma unroll
            for (int r = 0; r < 4; ++r) {
                float pe = __expf(st[mt][r] - mrun);
                st[mt][r] = pe;
                rs += pe;
            }
        }
        rs += __shfl_xor(rs, 16);
        rs += __shfl_xor(rs, 32);
        lrun += rs;

        // ---- pack P^T to bf16 ----
        union PK { int d[2]; __bf16 hh[4]; };
        PK pk0, pk1, pk2, pk3;
        pk0.hh[0]=(__bf16)st[0][0]; pk0.hh[1]=(__bf16)st[0][1]; pk0.hh[2]=(__bf16)st[0][2]; pk0.hh[3]=(__bf16)st[0][3];
        pk1.hh[0]=(__bf16)st[1][0]; pk1.hh[1]=(__bf16)st[1][1]; pk1.hh[2]=(__bf16)st[1][2]; pk1.hh[3]=(__bf16)st[1][3];
        pk2.hh[0]=(__bf16)st[2][0]; pk2.hh[1]=(__bf16)st[2][1]; pk2.hh[2]=(__bf16)st[2][2]; pk2.hh[3]=(__bf16)st[2][3];
        pk3.hh[0]=(__bf16)st[3][0]; pk3.hh[1]=(__bf16)st[3][1]; pk3.hh[2]=(__bf16)st[3][2]; pk3.hh[3]=(__bf16)st[3][3];

        // ---- assemble PV A-fragments via shuffles ----
        const int srcA = (l4 & 1) * 32 + l15;
        const int srcB = srcA + 16;
        const int sel  = l4 >> 1;
        s16x8 pa[2];
        {
            union { int d[4]; s16x8 v; } ua;
            int a00 = __shfl(pk0.d[0], srcA), a10 = __shfl(pk1.d[0], srcA);
            int a01 = __shfl(pk0.d[1], srcA), a11 = __shfl(pk1.d[1], srcA);
            int b00 = __shfl(pk0.d[0], srcB), b10 = __shfl(pk1.d[0], srcB);
            int b01 = __shfl(pk0.d[1], srcB), b11 = __shfl(pk1.d[1], srcB);
            ua.d[0] = sel ? a10 : a00; ua.d[1] = sel ? a11 : a01;
            ua.d[2] = sel ? b10 : b00; ua.d[3] = sel ? b11 : b01;
            pa[0] = ua.v;
        }
        {
            union { int d[4]; s16x8 v; } ua;
            int a00 = __shfl(pk2.d[0], srcA), a10 = __shfl(pk3.d[0], srcA);
            int a01 = __shfl(pk2.d[1], srcA), a11 = __shfl(pk3.d[1], srcA);
            int b00 = __shfl(pk2.d[0], srcB), b10 = __shfl(pk3.d[0], srcB);
            int b01 = __shfl(pk2.d[1], srcB), b11 = __shfl(pk3.d[1], srcB);
            ua.d[0] = sel ? a10 : a00; ua.d[1] = sel ? a11 : a01;
            ua.d[2] = sel ? b10 : b00; ua.d[3] = sel ? b11 : b01;
            pa[1] = ua.v;
        }

        // ---- O += P @ V ----
        #pragma unroll
        for (int nn = 0; nn < 8; ++nn) {
            s16x8 vf0 = *(const s16x8*)((const char*)Vt +
                          (nn * 16 + l15) * 128 + ((l4 * 16) ^ xv));
            s16x8 vf1 = *(const s16x8*)((const char*)Vt +
                          (nn * 16 + l15) * 128 + ((64 + l4 * 16) ^ xv));
            acc[nn] = MFMA16(pa[0], vf0, acc[nn]);
            acc[nn] = MFMA16(pa[1], vf1, acc[nn]);
        }
    }

    // ---- epilogue: store UNNORMALIZED partial O + per-row (m,l) ----
    float* obase = opart + (size_t)half * (B_ * NH_ * SQ_ * HD_) +
                   (((size_t)(b * NH_ + h)) * SQ_ + q0 + w * 16 + l4 * 4) * HD_ + l15;
    #pragma unroll
    for (int nn = 0; nn < 8; ++nn) {
        obase[(size_t)0 * HD_ + nn * 16] = acc[nn][0];
        obase[(size_t)1 * HD_ + nn * 16] = acc[nn][1];
        obase[(size_t)2 * HD_ + nn * 16] = acc[nn][2];
        obase[(size_t)3 * HD_ + nn * 16] = acc[nn][3];
    }
    if (l4 == 0) {
        int row = (b * NH_ + h) * SQ_ + q0 + w * 16 + l15;
        ml[half * (B_ * NH_ * SQ_) + row] = make_float2(mrun, lrun);
    }
}

// Combine the two KV-halves: O = (O0*e0 + O1*e1) / (l0*e0 + l1*e1)
__global__ void reduce_kernel(const float* __restrict__ part, const float2* __restrict__ ml,
                              float* __restrict__ ctx)
{
    int idx = blockIdx.x * 256 + threadIdx.x;          // 2.1M threads x float4
    int row = idx >> 5;                                 // (b*NH+h)*SQ + s
    int c4  = (idx & 31) * 4;
    float2 a = ml[row];
    float2 c = ml[(B_ * NH_ * SQ_) + row];
    float mm = fmaxf(a.x, c.x);
    float e0 = __expf(a.x - mm), e1 = __expf(c.x - mm);
    float inv = 1.f / (a.y * e0 + c.y * e1);
    const float4 o0 = *(const float4*)(part + (size_t)row * HD_ + c4);
    const float4 o1 = *(const float4*)(part + (size_t)(B_ * NH_ * SQ_) * HD_ +
                                       (size_t)row * HD_ + c4);
    float4 o;
    o.x = (o0.x * e0 + o1.x * e1) * inv;
    o.y = (o0.y * e0 + o1.y * e1) * inv;
    o.z = (o0.z * e0 + o1.z * e1) * inv;
    o.w = (o0.w * e0 + o1.w * e1) * inv;
    *(float4*)(ctx + (size_t)row * HD_ + c4) = o;
}

// cache_kv: out[b][s][part][h][d] = (part ? v : k)[b][h][s][d]
__global__ void cachekv_kernel(const float* __restrict__ k, const float* __restrict__ v,
                               float* __restrict__ out)
{
    size_t i = ((size_t)blockIdx.x * 256 + threadIdx.x) * 4;
    unsigned f = (unsigned)i;
    unsigned d    = f & 127;
    unsigned hh   = (f >> 7) & 31;
    unsigned part = (f >> 12) & 1;
    unsigned s    = (f >> 13) & 511;
    unsigned bb   = f >> 22;
    const float* src = (part ? v : k) + (((size_t)(bb * 32u + hh)) * 512u + s) * 128u + d;
    *(float4*)(out + i) = *(const float4*)src;
}

extern "C" void kernel_launch(void* const* d_in, const int* in_sizes, int n_in,
                              void* d_out, int out_size, void* d_ws, size_t ws_size,
                              hipStream_t stream) {
    const float* q    = (const float*)d_in[0];
    const float* k    = (const float*)d_in[1];
    const float* v    = (const float*)d_in[2];
    const float* mask = (const float*)d_in[3];
    const float* mem  = (const float*)d_in[4];
    float* out = (float*)d_out;

    const int ctx_elems = B_ * NH_ * SQ_ * HD_;                 // 8388608
    const int ckv_elems = B_ * SQ_ * 2 * NH_ * HD_;             // 16777216

    float*  part = out + ctx_elems;        // cachekv region doubles as partial-O
    float2* ml   = (float2*)d_ws;          // 2 * 65536 * 8B = 1 MB

    // 1) split attention -> unnormalized partials (in cachekv region) + (m,l) in ws
    attn_split_kernel<<<dim3(2 * B_ * NH_ * (SQ_ / QB_)), dim3(512), 0, stream>>>(
        q, k, v, mask, mem, part, ml);

    // 2) combine halves -> ctx
    reduce_kernel<<<dim3(ctx_elems / 4 / 256), dim3(256), 0, stream>>>(part, ml, out);

    // 3) cachekv overwrites the partial region with the real cache_kv output
    cachekv_kernel<<<dim3(ckv_elems / 4 / 256), dim3(256), 0, stream>>>(k, v, out + ctx_elems);

    (void)in_sizes; (void)n_in; (void)out_size; (void)ws_size;
}